// Round 5
// baseline (116.509 us; speedup 1.0000x reference)
//
#include <hip/hip_runtime.h>

// WaveletFilterNet fused: haar_forward -> per-channel filter -> haar_inverse
// x: (16,1,2048,2048) fp32, filt: (1,3,1024,1024) fp32, out: (16,1,2048,2048) fp32
//
// Per 2x2 input block {A,B,C,D}:
//   P=A+B+C+D, Q=A-B-C+D (HH), R=A+B-C-D (HL), S=A-B+C-D (LH)
// filt ch0 scales HH, ch1 scales HL, ch2 scales LH (reference returns LL,HH,HL,LH).
//   out[2i  ,2j]=.25(P+q+r+s)  out[2i  ,2j+1]=.25(P-q+r-s)
//   out[2i+1,2j]=.25(P+q-r-s)  out[2i+1,2j+1]=.25(P-q-r+s)
//
// R4 = R3 with the grid-size bug fixed: each thread covers 8 INPUT columns,
// so threads per row-pair = W_/8 = 256 (not W2_/8). Grid 16384, not 8192.

#define B_    16
#define H_    2048
#define W_    2048
#define H2_   1024
#define W2_   1024

typedef float f32x4 __attribute__((ext_vector_type(4)));

struct Quad { float o00, o01, o10, o11; };

__device__ __forceinline__ Quad haar_block(float A, float Bv, float C, float D,
                                           float f0, float f1, float f2)
{
    const float P = A + Bv + C + D;
    const float q = f0 * (A - Bv - C + D);   // HH
    const float r = f1 * (A + Bv - C - D);   // HL
    const float s = f2 * (A - Bv + C - D);   // LH
    Quad o;
    o.o00 = 0.25f * (P + q + r + s);
    o.o01 = 0.25f * (P - q + r - s);
    o.o10 = 0.25f * (P + q - r - s);
    o.o11 = 0.25f * (P - q - r + s);
    return o;
}

__global__ __launch_bounds__(256) void wavelet_fused_kernel(
    const float* __restrict__ x,
    const float* __restrict__ filt,
    float* __restrict__ out)
{
    // grid = 16384 blocks; 1024 spatial chunks/batch, batch innermost in bid.
    const unsigned bid = blockIdx.x;
    const unsigned b   = bid & 15u;
    const unsigned sp  = bid >> 4;            // block-row i in [0,1024)

    const unsigned i  = sp;
    const unsigned jt = threadIdx.x;          // 8-input-float chunk in row, [0,256)

    const long long inOff = (((long long)b * H_) + 2 * i) * W_ + (long long)jt * 8;

    const f32x4* xr0 = reinterpret_cast<const f32x4*>(x + inOff);
    const f32x4* xr1 = reinterpret_cast<const f32x4*>(x + inOff + W_);
    const f32x4 t0 = __builtin_nontemporal_load(xr0);
    const f32x4 t1 = __builtin_nontemporal_load(xr0 + 1);
    const f32x4 c0 = __builtin_nontemporal_load(xr1);
    const f32x4 c1 = __builtin_nontemporal_load(xr1 + 1);

    const long long fOff = (long long)i * W2_ + (long long)jt * 4;
    const f32x4 f0 = *reinterpret_cast<const f32x4*>(filt + 0 * (H2_ * W2_) + fOff); // HH
    const f32x4 f1 = *reinterpret_cast<const f32x4*>(filt + 1 * (H2_ * W2_) + fOff); // HL
    const f32x4 f2 = *reinterpret_cast<const f32x4*>(filt + 2 * (H2_ * W2_) + fOff); // LH

    const Quad q0 = haar_block(t0.x, t0.y, c0.x, c0.y, f0.x, f1.x, f2.x);
    const Quad q1 = haar_block(t0.z, t0.w, c0.z, c0.w, f0.y, f1.y, f2.y);
    const Quad q2 = haar_block(t1.x, t1.y, c1.x, c1.y, f0.z, f1.z, f2.z);
    const Quad q3 = haar_block(t1.z, t1.w, c1.z, c1.w, f0.w, f1.w, f2.w);

    f32x4 o0a, o0b, o1a, o1b;
    o0a.x = q0.o00; o0a.y = q0.o01; o0a.z = q1.o00; o0a.w = q1.o01;
    o1a.x = q0.o10; o1a.y = q0.o11; o1a.z = q1.o10; o1a.w = q1.o11;
    o0b.x = q2.o00; o0b.y = q2.o01; o0b.z = q3.o00; o0b.w = q3.o01;
    o1b.x = q2.o10; o1b.y = q2.o11; o1b.z = q3.o10; o1b.w = q3.o11;

    f32x4* or0 = reinterpret_cast<f32x4*>(out + inOff);
    f32x4* or1 = reinterpret_cast<f32x4*>(out + inOff + W_);
    __builtin_nontemporal_store(o0a, or0);
    __builtin_nontemporal_store(o0b, or0 + 1);
    __builtin_nontemporal_store(o1a, or1);
    __builtin_nontemporal_store(o1b, or1 + 1);
}

extern "C" void kernel_launch(void* const* d_in, const int* in_sizes, int n_in,
                              void* d_out, int out_size, void* d_ws, size_t ws_size,
                              hipStream_t stream) {
    const float* x    = (const float*)d_in[0];
    const float* filt = (const float*)d_in[1];
    float* out        = (float*)d_out;

    const unsigned total_threads = B_ * H2_ * (W_ / 8); // 16*1024*256 = 4,194,304
    const unsigned block = 256;
    const unsigned grid = total_threads / block;        // 16384
    wavelet_fused_kernel<<<grid, block, 0, stream>>>(x, filt, out);
}

// Round 6
// 108.406 us; speedup vs baseline: 1.0747x; 1.0747x over previous
//
#include <hip/hip_runtime.h>

// WaveletFilterNet fused: haar_forward -> per-channel filter -> haar_inverse
// x: (16,1,2048,2048) fp32, filt: (1,3,1024,1024) fp32, out: (16,1,2048,2048) fp32
//
// Per 2x2 input block {A,B,C,D}:
//   P=A+B+C+D, Q=A-B-C+D (HH), R=A+B-C-D (HL), S=A-B+C-D (LH)
// filt ch0 scales HH, ch1 scales HL, ch2 scales LH (reference returns LL,HH,HL,LH).
//   out[2i  ,2j]=.25(P+q+r+s)  out[2i  ,2j+1]=.25(P-q+r-s)
//   out[2i+1,2j]=.25(P+q-r-s)  out[2i+1,2j+1]=.25(P-q-r+s)
//
// R5 = R4 minus all nontemporal hints (plain vector loads/stores, like the
// 6.3 TB/s copy ubench). Keeps batch-inner swizzle (filter rows L2-resident
// per XCD: ~1.5 MB concurrent filter footprint < 4 MiB L2) and 4 haar-blocks
// per thread.

#define B_    16
#define H_    2048
#define W_    2048
#define H2_   1024
#define W2_   1024

typedef float f32x4 __attribute__((ext_vector_type(4)));

struct Quad { float o00, o01, o10, o11; };

__device__ __forceinline__ Quad haar_block(float A, float Bv, float C, float D,
                                           float f0, float f1, float f2)
{
    const float P = A + Bv + C + D;
    const float q = f0 * (A - Bv - C + D);   // HH
    const float r = f1 * (A + Bv - C - D);   // HL
    const float s = f2 * (A - Bv + C - D);   // LH
    Quad o;
    o.o00 = 0.25f * (P + q + r + s);
    o.o01 = 0.25f * (P - q + r - s);
    o.o10 = 0.25f * (P + q - r - s);
    o.o11 = 0.25f * (P - q - r + s);
    return o;
}

__global__ __launch_bounds__(256) void wavelet_fused_kernel(
    const float* __restrict__ x,
    const float* __restrict__ filt,
    float* __restrict__ out)
{
    // grid = 16384 blocks; batch innermost in bid so the 16 blocks sharing a
    // filter row run back-to-back (2 per XCD under bid%8 round-robin).
    const unsigned bid = blockIdx.x;
    const unsigned b   = bid & 15u;
    const unsigned i   = bid >> 4;            // block-row in [0,1024)

    const unsigned jt = threadIdx.x;          // 8-input-float chunk in row, [0,256)

    const long long inOff = (((long long)b * H_) + 2 * i) * W_ + (long long)jt * 8;

    const f32x4* xr0 = reinterpret_cast<const f32x4*>(x + inOff);
    const f32x4* xr1 = reinterpret_cast<const f32x4*>(x + inOff + W_);
    const f32x4 t0 = xr0[0];
    const f32x4 t1 = xr0[1];
    const f32x4 c0 = xr1[0];
    const f32x4 c1 = xr1[1];

    const long long fOff = (long long)i * W2_ + (long long)jt * 4;
    const f32x4 f0 = *reinterpret_cast<const f32x4*>(filt + 0 * (H2_ * W2_) + fOff); // HH
    const f32x4 f1 = *reinterpret_cast<const f32x4*>(filt + 1 * (H2_ * W2_) + fOff); // HL
    const f32x4 f2 = *reinterpret_cast<const f32x4*>(filt + 2 * (H2_ * W2_) + fOff); // LH

    const Quad q0 = haar_block(t0.x, t0.y, c0.x, c0.y, f0.x, f1.x, f2.x);
    const Quad q1 = haar_block(t0.z, t0.w, c0.z, c0.w, f0.y, f1.y, f2.y);
    const Quad q2 = haar_block(t1.x, t1.y, c1.x, c1.y, f0.z, f1.z, f2.z);
    const Quad q3 = haar_block(t1.z, t1.w, c1.z, c1.w, f0.w, f1.w, f2.w);

    f32x4 o0a, o0b, o1a, o1b;
    o0a.x = q0.o00; o0a.y = q0.o01; o0a.z = q1.o00; o0a.w = q1.o01;
    o1a.x = q0.o10; o1a.y = q0.o11; o1a.z = q1.o10; o1a.w = q1.o11;
    o0b.x = q2.o00; o0b.y = q2.o01; o0b.z = q3.o00; o0b.w = q3.o01;
    o1b.x = q2.o10; o1b.y = q2.o11; o1b.z = q3.o10; o1b.w = q3.o11;

    f32x4* or0 = reinterpret_cast<f32x4*>(out + inOff);
    f32x4* or1 = reinterpret_cast<f32x4*>(out + inOff + W_);
    or0[0] = o0a;
    or0[1] = o0b;
    or1[0] = o1a;
    or1[1] = o1b;
}

extern "C" void kernel_launch(void* const* d_in, const int* in_sizes, int n_in,
                              void* d_out, int out_size, void* d_ws, size_t ws_size,
                              hipStream_t stream) {
    const float* x    = (const float*)d_in[0];
    const float* filt = (const float*)d_in[1];
    float* out        = (float*)d_out;

    const unsigned total_threads = B_ * H2_ * (W_ / 8); // 16*1024*256 = 4,194,304
    const unsigned block = 256;
    const unsigned grid = total_threads / block;        // 16384
    wavelet_fused_kernel<<<grid, block, 0, stream>>>(x, filt, out);
}

// Round 7
// 101.165 us; speedup vs baseline: 1.1517x; 1.0716x over previous
//
#include <hip/hip_runtime.h>

// WaveletFilterNet fused: haar_forward -> per-channel filter -> haar_inverse
// x: (16,1,2048,2048) fp32, filt: (1,3,1024,1024) fp32, out: (16,1,2048,2048) fp32
//
// Per 2x2 input block {A,B,C,D}:
//   P=A+B+C+D, Q=A-B-C+D (HH), R=A+B-C-D (HL), S=A-B+C-D (LH)
// filt ch0 scales HH, ch1 scales HL, ch2 scales LH (reference returns LL,HH,HL,LH).
//   out[2i  ,2j]=.25(P+q+r+s)  out[2i  ,2j+1]=.25(P-q+r-s)
//   out[2i+1,2j]=.25(P+q-r-s)  out[2i+1,2j+1]=.25(P-q-r+s)
//
// R6: back to 1 float4 per row per thread (2 haar blocks) so every global
// load/store is 64 lanes x 16B CONTIGUOUS (1KB packed, copy-ubench pattern;
// R5's 32B/lane stride doubled cache-line transactions). Keeps batch-inner
// bid swizzle (filter rows L2/L3-hot) and plain (cached) loads.

#define B_    16
#define H_    2048
#define W_    2048
#define H2_   1024
#define W2_   1024

typedef float f32x4 __attribute__((ext_vector_type(4)));
typedef float f32x2 __attribute__((ext_vector_type(2)));

struct Quad { float o00, o01, o10, o11; };

__device__ __forceinline__ Quad haar_block(float A, float Bv, float C, float D,
                                           float f0, float f1, float f2)
{
    const float P = A + Bv + C + D;
    const float q = f0 * (A - Bv - C + D);   // HH
    const float r = f1 * (A + Bv - C - D);   // HL
    const float s = f2 * (A - Bv + C - D);   // LH
    Quad o;
    o.o00 = 0.25f * (P + q + r + s);
    o.o01 = 0.25f * (P - q + r - s);
    o.o10 = 0.25f * (P + q - r - s);
    o.o11 = 0.25f * (P - q - r + s);
    return o;
}

__global__ __launch_bounds__(256) void wavelet_fused_kernel(
    const float* __restrict__ x,
    const float* __restrict__ filt,
    float* __restrict__ out)
{
    // grid = 32768; bid = (spatial_chunk << 4) | batch. Each WG covers half a
    // row-pair: 256 threads x 1 float4 = 1024 input cols.
    const unsigned bid = blockIdx.x;
    const unsigned b   = bid & 15u;
    const unsigned sp  = bid >> 4;            // [0, 2048)
    const unsigned i   = sp >> 1;             // block-row in [0,1024)
    const unsigned jh  = sp & 1u;             // which half-row

    const unsigned jt = jh * 256u + threadIdx.x;   // float4 index in row, [0,512)

    const long long inOff = (((long long)b * H_) + 2 * i) * W_ + (long long)jt * 4;

    const f32x4 t0 = *reinterpret_cast<const f32x4*>(x + inOff);
    const f32x4 c0 = *reinterpret_cast<const f32x4*>(x + inOff + W_);

    const long long fOff = (long long)i * W2_ + (long long)jt * 2;
    const f32x2 f0 = *reinterpret_cast<const f32x2*>(filt + 0 * (H2_ * W2_) + fOff); // HH
    const f32x2 f1 = *reinterpret_cast<const f32x2*>(filt + 1 * (H2_ * W2_) + fOff); // HL
    const f32x2 f2 = *reinterpret_cast<const f32x2*>(filt + 2 * (H2_ * W2_) + fOff); // LH

    const Quad q0 = haar_block(t0.x, t0.y, c0.x, c0.y, f0.x, f1.x, f2.x);
    const Quad q1 = haar_block(t0.z, t0.w, c0.z, c0.w, f0.y, f1.y, f2.y);

    f32x4 o0, o1;
    o0.x = q0.o00; o0.y = q0.o01; o0.z = q1.o00; o0.w = q1.o01;
    o1.x = q0.o10; o1.y = q0.o11; o1.z = q1.o10; o1.w = q1.o11;

    *reinterpret_cast<f32x4*>(out + inOff)      = o0;
    *reinterpret_cast<f32x4*>(out + inOff + W_) = o1;
}

extern "C" void kernel_launch(void* const* d_in, const int* in_sizes, int n_in,
                              void* d_out, int out_size, void* d_ws, size_t ws_size,
                              hipStream_t stream) {
    const float* x    = (const float*)d_in[0];
    const float* filt = (const float*)d_in[1];
    float* out        = (float*)d_out;

    const unsigned total_threads = B_ * H2_ * (W_ / 4); // 16*1024*512 = 8,388,608
    const unsigned block = 256;
    const unsigned grid = total_threads / block;        // 32768
    wavelet_fused_kernel<<<grid, block, 0, stream>>>(x, filt, out);
}